// Round 2
// baseline (496.221 us; speedup 1.0000x reference)
//
#include <hip/hip_runtime.h>
#include <stdint.h>

#define M_TOK 256
#define N_OUT 16384
#define K_IN  4096
#define BM 64
#define BN 128
#define BK 64
#define NSTEPS (K_IN / BK)   // 64

#define AS1 __attribute__((address_space(1)))
#define AS3 __attribute__((address_space(3)))

typedef short v8s __attribute__((ext_vector_type(8)));
typedef float v16f __attribute__((ext_vector_type(16)));
typedef int   v4i __attribute__((ext_vector_type(4)));
typedef unsigned int uint;

__device__ __forceinline__ unsigned short rne_bf16(float f) {
  uint u = __float_as_uint(f);
  uint r = u + 0x7FFFu + ((u >> 16) & 1u);
  return (unsigned short)(r >> 16);
}
__device__ __forceinline__ float bfbits_to_f(uint h) {
  return __uint_as_float(h << 16);
}
// ints |v| <= 256 are exact in bf16: truncation of the f32 bits suffices
__device__ __forceinline__ uint pack_bf16(float a, float b) {
  return (__float_as_uint(a) >> 16) | (__float_as_uint(b) & 0xffff0000u);
}

// ---------------- kernel 1: exact dual-bf16 split of x (unchanged) ----------------
__global__ __launch_bounds__(256) void cast_kernel(
    const float* __restrict__ x, unsigned short* __restrict__ xhi,
    unsigned short* __restrict__ xlo) {
  const int i = (blockIdx.x * 256 + threadIdx.x) * 4;
  const float4 f = *(const float4*)(x + i);
  float fs[4] = {f.x, f.y, f.z, f.w};
  unsigned short h[4], l[4];
#pragma unroll
  for (int j = 0; j < 4; ++j) {
    h[j] = rne_bf16(fs[j]);
    l[j] = rne_bf16(fs[j] - bfbits_to_f(h[j]));
  }
  *(ushort4*)(xhi + i) = make_ushort4(h[0], h[1], h[2], h[3]);
  *(ushort4*)(xlo + i) = make_ushort4(l[0], l[1], l[2], l[3]);
}

// ---------------- kernel 2: pipelined dual-bf16 MFMA GEMM ----------------
// BM=64 BN=128 BK=64, 512 blocks (2 blocks/CU, 8 waves/CU for barrier-stagger TLP),
// 4 waves (2m x 2n), per-wave 32x64 tile via mfma_f32_32x32x16_bf16.
// LDS 64 KiB, all buffers double, ALL rows are 256 B with the round-0-proven
// 16-chunk XOR swizzle (chunk c of row r stored at pos c^(r&15)) -> every 16-lane
// phase of every LDS access covers 16 distinct 16B slots: zero bank conflicts.
//   xbuf  (2 x 16 KiB @0):     row r (0..63) = [xhi r: chunks 0..7 | xlo r: chunks 8..15]
//   wbuf  (2 x 16 KiB @32768): LDS row q (0..63) = [W row 2q | W row 2q+1] (bf16)
// Pipeline per step, ONE __syncthreads: stage(t+1) [x gload_lds + W reg loads] ->
// compute(t) -> convert+ds_write W(t+1) -> barrier. The other CU-resident block
// covers this block's barrier drain.
__global__ __launch_bounds__(256, 2) void gemm_kernel(
    const unsigned short* __restrict__ xhi, const unsigned short* __restrict__ xlo,
    const void* __restrict__ wraw, const float* __restrict__ scales,
    float* __restrict__ out) {
  __shared__ alignas(16) unsigned char smem[65536];
  const int tid = threadIdx.x;
  const int lane = tid & 63;
  const int wid = tid >> 6;

  // --- runtime dtype probe: 64B read, in-bounds under both layouts; uniform result
  const int* wi = (const int*)wraw;
  const signed char* wb = (const signed char*)wraw;
  bool is32 = true;
#pragma unroll
  for (int i = 0; i < 16; ++i) {
    const int v = wi[i];
    is32 = is32 && (v >= -128) && (v <= 127);
  }

  // XCD swizzle: the 4 mb-blocks sharing one W strip land on one XCD, close in time.
  const int bid = blockIdx.x;
  const int logical = (bid & 7) * 64 + (bid >> 3);  // bijective for 512
  const int mb = logical & 3;
  const int nb = logical >> 2;
  const int m0 = mb * BM;
  const int n0 = nb * BN;

  // --- x staging: per wave 4 gload_lds of 1 KiB (4 rows each); dest linear,
  // swizzle realized by pre-swizzling the per-lane GLOBAL source chunk.
  const unsigned short* xsrc[4];
  uint xdst[4];
#pragma unroll
  for (int j = 0; j < 4; ++j) {
    const int s = wid * 4 + j;                 // 0..15
    const int r = 4 * s + (lane >> 4);         // row 0..63
    const int c = (lane & 15) ^ (r & 15);      // global chunk living at pos lane&15
    xsrc[j] = xhi + (size_t)(c >> 3) * M_TOK * K_IN   // plane: 0=hi, 1=lo
            + (size_t)(m0 + r) * K_IN + (size_t)((c & 7) * 8);
    xdst[j] = (uint)(s * 1024);
  }

  // --- W staging (coalesced): int32 path: 8 iters, iter i: row = i*16 + (tid>>4),
  // 16B = 4 int32 at k-int32-offset (tid&15)*4. int8 path: 2 iters, row = i*64 +
  // (tid>>2), 16B = 16 int8 at byte offset (tid&3)*16.
  const int wr32 = tid >> 4, wc32 = tid & 15;
  const int* w32base = wi + (size_t)(n0 + wr32) * K_IN + (size_t)(wc32 * 4);
  const int wr8 = tid >> 2, wc8 = tid & 3;
  const signed char* w8base = wb + (size_t)(n0 + wr8) * K_IN + (size_t)(wc8 * 16);

  // --- compute descriptors (mfma_f32_32x32x16_bf16; A: row=l&31 k=(l>>5)*8..+8;
  // C/D: col=l&31, row=(reg&3)+8*(reg>>2)+4*(l>>5) — verified in prior rounds)
  const int l31 = lane & 31, hi5 = lane >> 5;
  const int wm = (wid & 1) * 32;
  const int wn = (wid >> 1) * 64;
  const uint abase = (uint)((wm + l31) * 256);
  const uint axor = (uint)((wm + l31) & 15);
  uint bbase[2], bxor[2], bsel[2];
#pragma unroll
  for (int nf = 0; nf < 2; ++nf) {
    const int wrow = wn + nf * 32 + l31;
    const int q = wrow >> 1;
    bbase[nf] = (uint)(q * 256);
    bxor[nf] = (uint)(q & 15);
    bsel[nf] = (uint)((wrow & 1) * 8);
  }

  v16f acc[2] = {};
  v4i wt[8];  // W stage regs (8 used on int32 path, 2 on int8 path)

  auto stage = [&](int s, uint xb) {
#pragma unroll
    for (int j = 0; j < 4; ++j)
      __builtin_amdgcn_global_load_lds(
          (const AS1 void*)(xsrc[j] + (size_t)s * BK),
          (AS3 void*)(smem + xb + xdst[j]), 16, 0, 0);
    if (is32) {
#pragma unroll
      for (int i = 0; i < 8; ++i)
        wt[i] = *(const v4i*)(w32base + (size_t)i * 16 * K_IN + (size_t)s * 64);
    } else {
#pragma unroll
      for (int i = 0; i < 2; ++i)
        wt[i] = *(const v4i*)(w8base + (size_t)i * 64 * K_IN + (size_t)s * 64);
    }
  };

  auto conv_write_w = [&](uint wo) {
    if (is32) {
#pragma unroll
      for (int i = 0; i < 8; ++i) {
        const int r = i * 16 + wr32;
        const int q = r >> 1;
        const int chunk = (r & 1) * 8 + (wc32 >> 1);
        const uint byte = wo + (uint)(q * 256) + (uint)((chunk ^ (q & 15)) << 4) +
                          (uint)((wc32 & 1) * 8);
        uint2 d;
        d.x = pack_bf16((float)wt[i].x, (float)wt[i].y);
        d.y = pack_bf16((float)wt[i].z, (float)wt[i].w);
        *(uint2*)(smem + byte) = d;
      }
    } else {
#pragma unroll
      for (int i = 0; i < 2; ++i) {
        const int r = i * 64 + wr8;
        const int q = r >> 1;
        const signed char* bs = (const signed char*)&wt[i];
        uint u[4];
#pragma unroll
        for (int p = 0; p < 4; ++p)
          u[p] = pack_bf16((float)bs[2 * p], (float)bs[2 * p + 1]);
        uint u2[4];
#pragma unroll
        for (int p = 0; p < 4; ++p)
          u2[p] = pack_bf16((float)bs[8 + 2 * p], (float)bs[8 + 2 * p + 1]);
        const int cb = (r & 1) * 8 + wc8 * 2;
        const uint b0 = wo + (uint)(q * 256) + (uint)(((cb + 0) ^ (q & 15)) << 4);
        const uint b1 = wo + (uint)(q * 256) + (uint)(((cb + 1) ^ (q & 15)) << 4);
        *(v4i*)(smem + b0) = *(v4i*)&u[0];
        *(v4i*)(smem + b1) = *(v4i*)&u2[0];
      }
    }
  };

  // prologue: stage step 0 into buffer 0
  stage(0, 0u);
  conv_write_w(32768u);  // compiler inserts the vmcnt wait on wt use
  __syncthreads();       // also drains the x gload_lds

  for (int t = 0; t < NSTEPS; ++t) {
    const uint cur = (uint)(t & 1) << 14;
    const uint xb = cur, wo = 32768u + cur;
    const uint nxb = xb ^ 16384u, nwo = wo ^ 16384u;
    const bool more = (t + 1 < NSTEPS);
    if (more) stage(t + 1, nxb);
    __builtin_amdgcn_sched_barrier(0);  // keep prefetch issue above compute

#pragma unroll
    for (int kc = 0; kc < 4; ++kc) {
      const uint ch = (uint)(kc * 2 + hi5);
      v8s ah = *(const v8s*)(smem + xb + abase + ((ch ^ axor) << 4));
      v8s al = *(const v8s*)(smem + xb + abase + (((ch + 8u) ^ axor) << 4));
      v8s b0 = *(const v8s*)(smem + wo + bbase[0] + (((bsel[0] + ch) ^ bxor[0]) << 4));
      v8s b1 = *(const v8s*)(smem + wo + bbase[1] + (((bsel[1] + ch) ^ bxor[1]) << 4));
      acc[0] = __builtin_amdgcn_mfma_f32_32x32x16_bf16(ah, b0, acc[0], 0, 0, 0);
      acc[0] = __builtin_amdgcn_mfma_f32_32x32x16_bf16(al, b0, acc[0], 0, 0, 0);
      acc[1] = __builtin_amdgcn_mfma_f32_32x32x16_bf16(ah, b1, acc[1], 0, 0, 0);
      acc[1] = __builtin_amdgcn_mfma_f32_32x32x16_bf16(al, b1, acc[1], 0, 0, 0);
    }

    if (more) conv_write_w(nwo);  // W(t+1) regs landed during compute
    __syncthreads();
  }

  // epilogue: C/D: col = lane&31, row = (reg&3) + 8*(reg>>2) + 4*(lane>>5)
#pragma unroll
  for (int nf = 0; nf < 2; ++nf) {
    const int n = n0 + wn + nf * 32 + l31;
    const float scl = scales[n];
#pragma unroll
    for (int reg = 0; reg < 16; ++reg) {
      const int m = m0 + wm + (reg & 3) + 8 * (reg >> 2) + 4 * hi5;
      out[(size_t)m * N_OUT + n] = acc[nf][reg] * scl;
    }
  }
}

// ---------------- fallback (workspace too small); also dtype-probed ----------------
__global__ void naive_kernel(const float* __restrict__ x, const void* __restrict__ wraw,
                             const float* __restrict__ scales, float* __restrict__ out) {
  const int* wi = (const int*)wraw;
  bool is32 = true;
  for (int i = 0; i < 16; ++i) { int v = wi[i]; is32 = is32 && v >= -128 && v <= 127; }
  const int idx = blockIdx.x * 256 + threadIdx.x;
  const int m = idx >> 14;
  const int n = idx & (N_OUT - 1);
  const float* xr = x + (size_t)m * K_IN;
  float acc = 0.f;
  if (is32) {
    const int* wr = wi + (size_t)n * K_IN;
    for (int k = 0; k < K_IN; ++k) acc += xr[k] * (float)wr[k];
  } else {
    const signed char* wr = (const signed char*)wraw + (size_t)n * K_IN;
    for (int k = 0; k < K_IN; ++k) acc += xr[k] * (float)wr[k];
  }
  out[idx] = acc * scales[n];
}

extern "C" void kernel_launch(void* const* d_in, const int* in_sizes, int n_in,
                              void* d_out, int out_size, void* d_ws, size_t ws_size,
                              hipStream_t stream) {
  const float* x = (const float*)d_in[0];
  const void* w = d_in[1];  // dtype resolved on-device (int8 vs int32 materialization)
  const float* scales = (const float*)d_in[2];
  float* out = (float*)d_out;
  if (ws_size >= (size_t)4 * 1024 * 1024) {
    unsigned short* xhi = (unsigned short*)d_ws;
    unsigned short* xlo = xhi + (size_t)M_TOK * K_IN;
    cast_kernel<<<(M_TOK * K_IN) / 1024, 256, 0, stream>>>(x, xhi, xlo);
    gemm_kernel<<<512, 256, 0, stream>>>(xhi, xlo, w, scales, out);
  } else {
    naive_kernel<<<(M_TOK * N_OUT) / 256, 256, 0, stream>>>(x, w, scales, out);
  }
}

// Round 3
// 470.998 us; speedup vs baseline: 1.0536x; 1.0536x over previous
//
#include <hip/hip_runtime.h>
#include <stdint.h>

#define M_TOK 256
#define N_OUT 16384
#define K_IN  4096
#define BM 64
#define BN 128
#define BK 128
#define NSTEPS (K_IN / BK)   // 32

#define AS1 __attribute__((address_space(1)))
#define AS3 __attribute__((address_space(3)))

typedef short v8s __attribute__((ext_vector_type(8)));
typedef float v16f __attribute__((ext_vector_type(16)));
typedef int   v4i __attribute__((ext_vector_type(4)));
typedef unsigned int uint;

__device__ __forceinline__ unsigned short rne_bf16(float f) {
  uint u = __float_as_uint(f);
  uint r = u + 0x7FFFu + ((u >> 16) & 1u);
  return (unsigned short)(r >> 16);
}
__device__ __forceinline__ float bfbits_to_f(uint h) {
  return __uint_as_float(h << 16);
}
// ints |v| <= 256 are exact in bf16: truncation of the f32 bits suffices
__device__ __forceinline__ uint pack_bf16(float a, float b) {
  return (__float_as_uint(a) >> 16) | (__float_as_uint(b) & 0xffff0000u);
}

// ---------------- kernel 1: exact dual-bf16 split of x (unchanged) ----------------
__global__ __launch_bounds__(256) void cast_kernel(
    const float* __restrict__ x, unsigned short* __restrict__ xhi,
    unsigned short* __restrict__ xlo) {
  const int i = (blockIdx.x * 256 + threadIdx.x) * 4;
  const float4 f = *(const float4*)(x + i);
  float fs[4] = {f.x, f.y, f.z, f.w};
  unsigned short h[4], l[4];
#pragma unroll
  for (int j = 0; j < 4; ++j) {
    h[j] = rne_bf16(fs[j]);
    l[j] = rne_bf16(fs[j] - bfbits_to_f(h[j]));
  }
  *(ushort4*)(xhi + i) = make_ushort4(h[0], h[1], h[2], h[3]);
  *(ushort4*)(xlo + i) = make_ushort4(l[0], l[1], l[2], l[3]);
}

// ---------------- kernel 2: counted-vmcnt pipelined dual-bf16 MFMA GEMM ----------------
// BM=64 BN=128 BK=128, 512 blocks (2/CU), 4 waves (2m x 2n), 32x32x16 MFMA.
// LDS 64 KiB single-buffered: xhi[64][256B] @0, xlo @16384, W bf16 [128][256B] @32768.
// All rows 256 B, chunk c of row r at pos c^(r&15): zero bank conflicts (measured r0/r2).
// Schedule per step (RAW s_barrier, counted waits — W reg-loads span barriers):
//   compute(t)                                  <- W(t+1) 16 loads stay IN FLIGHT here
//   lgkmcnt(0); s_barrier                       <- barrier1: NO vmcnt drain
//   issue x(t+1) gload_lds (8/wave, oldest)
//   convert wt=W(t+1) -> ds_write               <- compiler auto-wait leaves x flying
//   issue W(t+2) -> wt (newest)
//   s_waitcnt vmcnt(16|4)                       <- waits ONLY the 8 x gloads
//   lgkmcnt(0); s_barrier                       <- barrier2: publish, W(t+2) still flying
__global__ __launch_bounds__(256, 2) void gemm_kernel(
    const unsigned short* __restrict__ xhi, const unsigned short* __restrict__ xlo,
    const void* __restrict__ wraw, const float* __restrict__ scales,
    float* __restrict__ out) {
  __shared__ alignas(16) unsigned char smem[65536];
  const int tid = threadIdx.x;
  const int lane = tid & 63;
  const int wid = tid >> 6;

  // --- runtime dtype probe: 64B read, in-bounds under both layouts; uniform result
  const int* wi = (const int*)wraw;
  const signed char* wb = (const signed char*)wraw;
  bool is32 = true;
#pragma unroll
  for (int i = 0; i < 16; ++i) {
    const int v = wi[i];
    is32 = is32 && (v >= -128) && (v <= 127);
  }

  // XCD swizzle: the 4 mb-blocks sharing one W strip land on one XCD, close in time.
  const int bid = blockIdx.x;
  const int logical = (bid & 7) * 64 + (bid >> 3);  // bijective for 512
  const int mb = logical & 3;
  const int nb = logical >> 2;
  const int m0 = mb * BM;
  const int n0 = nb * BN;

  // --- x staging: 32 wave-instrs of 1 KiB gload_lds; dest linear (base + lane*16),
  // swizzle realized by pre-swizzling the per-lane GLOBAL source chunk.
  const unsigned short* xsrc[8];
  uint xdst[8];
#pragma unroll
  for (int j = 0; j < 8; ++j) {
    const int s = wid * 8 + j;            // 0..31
    const int plane = s >> 4;             // 0: hi, 1: lo
    const int sp = s & 15;
    const int r = sp * 4 + (lane >> 4);   // row 0..63
    const int p = (lane & 15) ^ (r & 15); // global chunk living at LDS pos lane&15
    xsrc[j] = (plane ? xlo : xhi) + (size_t)(m0 + r) * K_IN + (size_t)(p * 8);
    xdst[j] = (uint)(plane * 16384 + sp * 1024);
  }

  // --- W staging descriptors (coalesced):
  // int32: 16 loads/thread; i: row = i*8 + (tid>>5), 16B chunk c32 = tid&31 of 512B row
  const int trow = tid >> 5, c32 = tid & 31;
  const int* w32base = wi + (size_t)(n0 + trow) * K_IN + (size_t)(c32 * 4);
  // int8: 4 loads/thread; i: row = i*32 + (tid>>3), 16B chunk c8 = tid&7 of 128B row
  const int r8 = tid >> 3, c8 = tid & 7;
  const signed char* w8base = wb + (size_t)(n0 + r8) * K_IN + (size_t)(c8 * 16);

  // --- compute descriptors (mfma_f32_32x32x16_bf16; A row=l&31, k-half=(l>>5);
  // C/D col=l&31, row=(reg&3)+8*(reg>>2)+4*(l>>5) — verified)
  const int l31 = lane & 31, hi5 = lane >> 5;
  const int wm = (wid & 1) * 32;
  const int wn = (wid >> 1) * 64;
  const uint arow = (uint)((wm + l31) * 256);
  const uint axor = (uint)((wm + l31) & 15);
  uint brow[2], bxor[2];
#pragma unroll
  for (int nf = 0; nf < 2; ++nf) {
    const int wr = wn + nf * 32 + l31;
    brow[nf] = 32768u + (uint)(wr * 256);
    bxor[nf] = (uint)(wr & 15);
  }

  v16f acc[2] = {};
  v4i wt[16];  // W reg pipeline (16 used on int32 path, 4 on int8 path)

  auto stage_x = [&](int s) {
#pragma unroll
    for (int j = 0; j < 8; ++j)
      __builtin_amdgcn_global_load_lds(
          (const AS1 void*)(xsrc[j] + (size_t)s * BK),
          (AS3 void*)(smem + xdst[j]), 16, 0, 0);
  };
  auto load_w = [&](int s) {
    if (is32) {
#pragma unroll
      for (int i = 0; i < 16; ++i)
        wt[i] = *(const v4i*)(w32base + (size_t)i * 8 * K_IN + (size_t)s * BK);
    } else {
#pragma unroll
      for (int i = 0; i < 4; ++i)
        wt[i] = *(const v4i*)(w8base + (size_t)i * 32 * K_IN + (size_t)s * BK);
    }
  };
  auto conv_w = [&]() {
    if (is32) {
#pragma unroll
      for (int i = 0; i < 16; ++i) {
        const int row = i * 8 + trow;
        const uint a = 32768u + (uint)(row * 256) +
                       (uint)(((c32 >> 1) ^ (row & 15)) << 4) + (uint)((c32 & 1) * 8);
        uint2 d;
        d.x = pack_bf16((float)wt[i].x, (float)wt[i].y);
        d.y = pack_bf16((float)wt[i].z, (float)wt[i].w);
        *(uint2*)(smem + a) = d;
      }
    } else {
#pragma unroll
      for (int i = 0; i < 4; ++i) {
        const int row = i * 32 + r8;
        const signed char* bs = (const signed char*)&wt[i];
        uint u0[4], u1[4];
#pragma unroll
        for (int p = 0; p < 4; ++p) {
          u0[p] = pack_bf16((float)bs[2 * p], (float)bs[2 * p + 1]);
          u1[p] = pack_bf16((float)bs[8 + 2 * p], (float)bs[8 + 2 * p + 1]);
        }
        const uint base = 32768u + (uint)(row * 256);
        const uint a0 = base + (uint)(((2 * c8 + 0) ^ (row & 15)) << 4);
        const uint a1 = base + (uint)(((2 * c8 + 1) ^ (row & 15)) << 4);
        *(v4i*)(smem + a0) = *(v4i*)&u0[0];
        *(v4i*)(smem + a1) = *(v4i*)&u1[0];
      }
    }
  };

  // ---- prologue: stage step 0, prefetch W(1)
  stage_x(0);
  load_w(0);
  conv_w();    // auto vmcnt wait (also drains x(0) — one-time)
  load_w(1);   // W(1) in flight across the barrier
  asm volatile("s_waitcnt lgkmcnt(0)" ::: "memory");
  __builtin_amdgcn_s_barrier();
  __builtin_amdgcn_sched_barrier(0);

  for (int t = 0;; ++t) {
    // ---- compute(t); W(t+1) loads remain in flight the whole time
#pragma unroll
    for (int kc = 0; kc < 8; ++kc) {
      const uint ch = (uint)(kc * 2 + hi5);
      v8s ah = *(const v8s*)(smem + arow + ((ch ^ axor) << 4));
      v8s al = *(const v8s*)(smem + 16384u + arow + ((ch ^ axor) << 4));
      v8s b0 = *(const v8s*)(smem + brow[0] + ((ch ^ bxor[0]) << 4));
      v8s b1 = *(const v8s*)(smem + brow[1] + ((ch ^ bxor[1]) << 4));
      acc[0] = __builtin_amdgcn_mfma_f32_32x32x16_bf16(ah, b0, acc[0], 0, 0, 0);
      acc[0] = __builtin_amdgcn_mfma_f32_32x32x16_bf16(al, b0, acc[0], 0, 0, 0);
      acc[1] = __builtin_amdgcn_mfma_f32_32x32x16_bf16(ah, b1, acc[1], 0, 0, 0);
      acc[1] = __builtin_amdgcn_mfma_f32_32x32x16_bf16(al, b1, acc[1], 0, 0, 0);
    }
    if (t == NSTEPS - 1) break;

    // ---- barrier1: readers done; NO vmcnt drain (W(t+1) stays in flight)
    asm volatile("s_waitcnt lgkmcnt(0)" ::: "memory");
    __builtin_amdgcn_s_barrier();
    __builtin_amdgcn_sched_barrier(0);

    stage_x(t + 1);            // x gloads: oldest of the new batch
    conv_w();                  // waits W(t+1) only (older than x) -> ds_write
    asm volatile("" ::: "memory");   // pin: x gloads + conv before W(t+2) issue
    const int wnext = (t + 2 < NSTEPS) ? t + 2 : NSTEPS - 1;
    load_w(wnext);             // newest; stays in flight across barrier2
    if (is32) asm volatile("s_waitcnt vmcnt(16)" ::: "memory");  // x done, W flying
    else      asm volatile("s_waitcnt vmcnt(4)" ::: "memory");
    asm volatile("s_waitcnt lgkmcnt(0)" ::: "memory");
    __builtin_amdgcn_s_barrier();   // barrier2: publish x+W LDS for step t+1
    __builtin_amdgcn_sched_barrier(0);
  }

  // ---- epilogue: C/D col = lane&31, row = (reg&3) + 8*(reg>>2) + 4*(lane>>5)
#pragma unroll
  for (int nf = 0; nf < 2; ++nf) {
    const int n = n0 + wn + nf * 32 + l31;
    const float scl = scales[n];
#pragma unroll
    for (int reg = 0; reg < 16; ++reg) {
      const int m = m0 + wm + (reg & 3) + 8 * (reg >> 2) + 4 * hi5;
      out[(size_t)m * N_OUT + n] = acc[nf][reg] * scl;
    }
  }
}

// ---------------- fallback (workspace too small); also dtype-probed ----------------
__global__ void naive_kernel(const float* __restrict__ x, const void* __restrict__ wraw,
                             const float* __restrict__ scales, float* __restrict__ out) {
  const int* wi = (const int*)wraw;
  bool is32 = true;
  for (int i = 0; i < 16; ++i) { int v = wi[i]; is32 = is32 && v >= -128 && v <= 127; }
  const int idx = blockIdx.x * 256 + threadIdx.x;
  const int m = idx >> 14;
  const int n = idx & (N_OUT - 1);
  const float* xr = x + (size_t)m * K_IN;
  float acc = 0.f;
  if (is32) {
    const int* wr = wi + (size_t)n * K_IN;
    for (int k = 0; k < K_IN; ++k) acc += xr[k] * (float)wr[k];
  } else {
    const signed char* wr = (const signed char*)wraw + (size_t)n * K_IN;
    for (int k = 0; k < K_IN; ++k) acc += xr[k] * (float)wr[k];
  }
  out[idx] = acc * scales[n];
}

extern "C" void kernel_launch(void* const* d_in, const int* in_sizes, int n_in,
                              void* d_out, int out_size, void* d_ws, size_t ws_size,
                              hipStream_t stream) {
  const float* x = (const float*)d_in[0];
  const void* w = d_in[1];  // dtype resolved on-device (int8 vs int32 materialization)
  const float* scales = (const float*)d_in[2];
  float* out = (float*)d_out;
  if (ws_size >= (size_t)4 * 1024 * 1024) {
    unsigned short* xhi = (unsigned short*)d_ws;
    unsigned short* xlo = xhi + (size_t)M_TOK * K_IN;
    cast_kernel<<<(M_TOK * K_IN) / 1024, 256, 0, stream>>>(x, xhi, xlo);
    gemm_kernel<<<512, 256, 0, stream>>>(xhi, xlo, w, scales, out);
  } else {
    naive_kernel<<<(M_TOK * N_OUT) / 256, 256, 0, stream>>>(x, w, scales, out);
  }
}

// Round 4
// 407.405 us; speedup vs baseline: 1.2180x; 1.1561x over previous
//
#include <hip/hip_runtime.h>
#include <stdint.h>

#define M_TOK 256
#define N_OUT 16384
#define K_IN  4096
#define BM 128
#define BN 64
#define BK 64
#define NSTEPS (K_IN / BK)   // 64

#define AS1 __attribute__((address_space(1)))
#define AS3 __attribute__((address_space(3)))

typedef short v8s __attribute__((ext_vector_type(8)));
typedef float v16f __attribute__((ext_vector_type(16)));
typedef int   v4i __attribute__((ext_vector_type(4)));
typedef unsigned int uint;

__device__ __forceinline__ unsigned short rne_bf16(float f) {
  uint u = __float_as_uint(f);
  uint r = u + 0x7FFFu + ((u >> 16) & 1u);
  return (unsigned short)(r >> 16);
}
__device__ __forceinline__ float bfbits_to_f(uint h) {
  return __uint_as_float(h << 16);
}
// ints |v| <= 256 are exact in bf16: truncation of the f32 bits suffices
__device__ __forceinline__ uint pack_bf16(float a, float b) {
  return (__float_as_uint(a) >> 16) | (__float_as_uint(b) & 0xffff0000u);
}

// ---------------- kernel 1: exact dual-bf16 split of x (unchanged) ----------------
__global__ __launch_bounds__(256) void cast_kernel(
    const float* __restrict__ x, unsigned short* __restrict__ xhi,
    unsigned short* __restrict__ xlo) {
  const int i = (blockIdx.x * 256 + threadIdx.x) * 4;
  const float4 f = *(const float4*)(x + i);
  float fs[4] = {f.x, f.y, f.z, f.w};
  unsigned short h[4], l[4];
#pragma unroll
  for (int j = 0; j < 4; ++j) {
    h[j] = rne_bf16(fs[j]);
    l[j] = rne_bf16(fs[j] - bfbits_to_f(h[j]));
  }
  *(ushort4*)(xhi + i) = make_ushort4(h[0], h[1], h[2], h[3]);
  *(ushort4*)(xlo + i) = make_ushort4(l[0], l[1], l[2], l[3]);
}

// ---------------- kernel 2: dual-bf16 MFMA GEMM, cache-traffic-minimized ----------------
// BM=128 BN=64 BK=64, 512 blocks x 512 threads (2 blocks/CU, 16 waves/CU).
// W strip shared by only TWO mb-blocks, XCD-paired -> W crosses L3 ~once (~256 MiB).
// LDS 40 KiB: x[128 rows][256B] @0 (hi = chunks 0-7, lo = chunks 8-15);
//             W  [32 rows][256B] @32768 (LDS row q packs n-rows 2q | 2q+1).
// All rows 256 B, chunk c of row r at pos c^(r&15): zero conflicts (measured r0/r2/r3).
// Plain two-barrier step (no asm waitcnts -> no spills); only W(t+1)'s 2 dwordx4
// (8 VGPR) are issued early, at the top of the compute phase, so their latency
// hides under the MFMAs and the barrier's auto-drain sees only the residual.
__global__ __launch_bounds__(512, 4) void gemm_kernel(
    const unsigned short* __restrict__ xhi, const unsigned short* __restrict__ xlo,
    const void* __restrict__ wraw, const float* __restrict__ scales,
    float* __restrict__ out) {
  __shared__ alignas(16) unsigned char smem[40960];
  const int tid = threadIdx.x;
  const int lane = tid & 63;
  const int wid = tid >> 6;

  // --- runtime dtype probe: 64B read, in-bounds under both layouts; uniform result
  const int* wi = (const int*)wraw;
  const signed char* wb = (const signed char*)wraw;
  bool is32 = true;
#pragma unroll
  for (int i = 0; i < 16; ++i) {
    const int v = wi[i];
    is32 = is32 && (v >= -128) && (v <= 127);
  }

  // XCD swizzle: the 2 mb-blocks sharing one W strip are adjacent on one XCD.
  const int bid = blockIdx.x;
  const int logical = (bid & 7) * 64 + (bid >> 3);  // bijective for 512
  const int mb = logical & 1;
  const int nb = logical >> 1;
  const int m0 = mb * BM;
  const int n0 = nb * BN;

  // --- x staging: 4 gload_lds per thread (32 KiB/step); dest linear (base+lane*16),
  // swizzle realized by pre-swizzling the per-lane GLOBAL source chunk.
  const unsigned short* xsrc[4];
  uint xdst[4];
#pragma unroll
  for (int j = 0; j < 4; ++j) {
    const int s = wid * 4 + j;              // 0..31, each stages 4 rows (1 KiB)
    const int r = s * 4 + (lane >> 4);      // row 0..127
    const int c = (lane & 15) ^ (r & 15);   // chunk living at LDS pos lane&15
    xsrc[j] = (c >= 8 ? xlo : xhi) + (size_t)(m0 + r) * K_IN + (size_t)((c & 7) * 8);
    xdst[j] = (uint)(s * 1024);
  }

  // --- W staging: thread t owns row t>>3 (0..63), 32B span wc = t&7 (coalesced).
  const int wrow = tid >> 3, wc = tid & 7;
  const int* w32base = wi + (size_t)(n0 + wrow) * K_IN + (size_t)(wc * 8);
  const signed char* w8base = wb + (size_t)(n0 + wrow) * K_IN + (size_t)(wc * 8);
  // LDS target: one ds_write_b128 per thread
  const uint wq = (uint)(wrow >> 1);
  const uint wchunk = (uint)((wrow & 1) * 8 + wc);
  const uint waddr = 32768u + wq * 256u + ((wchunk ^ (wq & 15u)) << 4);

  // --- compute descriptors (mfma_f32_32x32x16_bf16; verified layouts)
  const int l31 = lane & 31, hi5 = lane >> 5;
  const int wm = (wid & 3) * 32;        // 4 m-waves
  const int wn = (wid >> 2) * 32;       // 2 n-waves
  const uint abase = (uint)((wm + l31) * 256);
  const uint ax = (uint)((wm + l31) & 15);
  const int wr = wn + l31;              // W n-row 0..63
  const uint bq = (uint)(wr >> 1);
  const uint bbase = 32768u + bq * 256u;
  const uint bsel = (uint)((wr & 1) * 8);
  const uint bx = bq & 15u;

  v16f acc = {};
  v4i wt0, wt1;  // W stage regs (8 VGPR; int8 path uses low half of wt0/wt1)

  auto stage_x = [&](int s) {
#pragma unroll
    for (int j = 0; j < 4; ++j)
      __builtin_amdgcn_global_load_lds(
          (const AS1 void*)(xsrc[j] + (size_t)s * BK),
          (AS3 void*)(smem + xdst[j]), 16, 0, 0);
  };
  auto load_w = [&](int s) {
    if (is32) {
      wt0 = *(const v4i*)(w32base + (size_t)s * BK);
      wt1 = *(const v4i*)(w32base + (size_t)s * BK + 4);
    } else {
      const uint2 u = *(const uint2*)(w8base + (size_t)s * BK);
      wt0.x = (int)u.x; wt0.y = (int)u.y;
    }
  };
  auto conv_w = [&]() {
    uint d[4];
    if (is32) {
      d[0] = pack_bf16((float)wt0.x, (float)wt0.y);
      d[1] = pack_bf16((float)wt0.z, (float)wt0.w);
      d[2] = pack_bf16((float)wt1.x, (float)wt1.y);
      d[3] = pack_bf16((float)wt1.z, (float)wt1.w);
    } else {
      const signed char* bs = (const signed char*)&wt0;  // 8 bytes in wt0.x/.y
#pragma unroll
      for (int p = 0; p < 4; ++p)
        d[p] = pack_bf16((float)bs[2 * p], (float)bs[2 * p + 1]);
    }
    v4i wv; wv.x = (int)d[0]; wv.y = (int)d[1]; wv.z = (int)d[2]; wv.w = (int)d[3];
    *(v4i*)(smem + waddr) = wv;
  };

  // ---- prologue
  stage_x(0);
  load_w(0);

  for (int t = 0; t < NSTEPS; ++t) {
    conv_w();            // auto-waits wt; ds_write W(t)
    __syncthreads();     // publish x(t)+W(t) (drains x gloads issued last iter)

    if (t + 1 < NSTEPS) load_w(t + 1);  // early issue; hides under the MFMAs

#pragma unroll
    for (int kc = 0; kc < 4; ++kc) {
      const uint ch = (uint)(kc * 2 + hi5);
      v8s ah = *(const v8s*)(smem + abase + ((ch ^ ax) << 4));
      v8s al = *(const v8s*)(smem + abase + (((ch + 8u) ^ ax) << 4));
      v8s b  = *(const v8s*)(smem + bbase + (((bsel + ch) ^ bx) << 4));
      acc = __builtin_amdgcn_mfma_f32_32x32x16_bf16(ah, b, acc, 0, 0, 0);
      acc = __builtin_amdgcn_mfma_f32_32x32x16_bf16(al, b, acc, 0, 0, 0);
    }

    __syncthreads();     // compute(t) done; buffer free (drains W(t+1) residual)
    if (t + 1 < NSTEPS) stage_x(t + 1);
  }

  // ---- epilogue: C/D col = lane&31, row = (reg&3) + 8*(reg>>2) + 4*(lane>>5)
  const int n = n0 + wn + l31;
  const float scl = scales[n];
#pragma unroll
  for (int reg = 0; reg < 16; ++reg) {
    const int m = m0 + wm + (reg & 3) + 8 * (reg >> 2) + 4 * hi5;
    out[(size_t)m * N_OUT + n] = acc[reg] * scl;
  }
}

// ---------------- fallback (workspace too small); also dtype-probed ----------------
__global__ void naive_kernel(const float* __restrict__ x, const void* __restrict__ wraw,
                             const float* __restrict__ scales, float* __restrict__ out) {
  const int* wi = (const int*)wraw;
  bool is32 = true;
  for (int i = 0; i < 16; ++i) { int v = wi[i]; is32 = is32 && v >= -128 && v <= 127; }
  const int idx = blockIdx.x * 256 + threadIdx.x;
  const int m = idx >> 14;
  const int n = idx & (N_OUT - 1);
  const float* xr = x + (size_t)m * K_IN;
  float acc = 0.f;
  if (is32) {
    const int* wr = wi + (size_t)n * K_IN;
    for (int k = 0; k < K_IN; ++k) acc += xr[k] * (float)wr[k];
  } else {
    const signed char* wr = (const signed char*)wraw + (size_t)n * K_IN;
    for (int k = 0; k < K_IN; ++k) acc += xr[k] * (float)wr[k];
  }
  out[idx] = acc * scales[n];
}

extern "C" void kernel_launch(void* const* d_in, const int* in_sizes, int n_in,
                              void* d_out, int out_size, void* d_ws, size_t ws_size,
                              hipStream_t stream) {
  const float* x = (const float*)d_in[0];
  const void* w = d_in[1];  // dtype resolved on-device (int8 vs int32 materialization)
  const float* scales = (const float*)d_in[2];
  float* out = (float*)d_out;
  if (ws_size >= (size_t)4 * 1024 * 1024) {
    unsigned short* xhi = (unsigned short*)d_ws;
    unsigned short* xlo = xhi + (size_t)M_TOK * K_IN;
    cast_kernel<<<(M_TOK * K_IN) / 1024, 256, 0, stream>>>(x, xhi, xlo);
    gemm_kernel<<<512, 512, 0, stream>>>(xhi, xlo, w, scales, out);
  } else {
    naive_kernel<<<(M_TOK * N_OUT) / 256, 256, 0, stream>>>(x, w, scales, out);
  }
}